// Round 2
// baseline (494.300 us; speedup 1.0000x reference)
//
#include <hip/hip_runtime.h>
#include <math.h>

#pragma clang fp contract(off)

#define NBINS 36
#define PS 32

typedef float f32x2 __attribute__((ext_vector_type(2)));

// CDNA packed-f32 VOP3P (full-rate, gfx90a+): IEEE f32 per half, identical
// rounding to scalar v_mul/v_add/v_fma. Emitted via asm so mul/add stay
// separate (contract off) and packing is guaranteed.
__device__ __forceinline__ f32x2 pk_mul(f32x2 a, f32x2 b) {
    f32x2 d;
    asm("v_pk_mul_f32 %0, %1, %2" : "=v"(d) : "v"(a), "v"(b));
    return d;
}
__device__ __forceinline__ f32x2 pk_add(f32x2 a, f32x2 b) {
    f32x2 d;
    asm("v_pk_add_f32 %0, %1, %2" : "=v"(d) : "v"(a), "v"(b));
    return d;
}
__device__ __forceinline__ f32x2 pk_sub(f32x2 a, f32x2 b) {   // a + (-b), IEEE == a-b
    f32x2 d;
    asm("v_pk_add_f32 %0, %1, %2 neg_lo:[0,1] neg_hi:[0,1]" : "=v"(d) : "v"(a), "v"(b));
    return d;
}
__device__ __forceinline__ f32x2 pk_fma(f32x2 a, f32x2 b, f32x2 c) {
    f32x2 d;
    asm("v_pk_fma_f32 %0, %1, %2, %3" : "=v"(d) : "v"(a), "v"(b), "v"(c));
    return d;
}

// Slim branchless f64 atan2, rounded to f32 (absmax 0.0 R5-R8).
// R8: single-NR division + folded atc_lo. Same <=~0.5ulp-of-f64 class.
__device__ __forceinline__ float atan2_np(float fy, float fx)
{
    const double aT0  =  3.33333333333329318027e-01;
    const double aT1  = -1.99999999998764832476e-01;
    const double aT2  =  1.42857142725034663711e-01;
    const double aT3  = -1.11111104054623557880e-01;
    const double aT4  =  9.09088713343650656196e-02;
    const double aT5  = -7.69187620504482999495e-02;
    const double aT6  =  6.66107313738753120669e-02;
    const double aT7  = -5.83357013379057348645e-02;
    const double aT8  =  4.97687799461593236017e-02;
    const double aT9  = -3.65315727442169155270e-02;
    const double aT10 =  1.62858201153657823623e-02;

    float axf = fabsf(fx), ayf = fabsf(fy);
    float uf = fmaxf(axf, ayf), vf = fminf(axf, ayf);
    bool g1 = vf >= 0.41421356f * uf;          // ~tan(pi/8); either branch valid near cut

    double u = (double)uf, v = (double)vf;
    double c      = g1 ? 1.0 : 0.0;
    double atc_hi = g1 ? 7.85398163397448278999e-01 : 0.0;
    double atc_lo = g1 ? 3.06161699786838301793e-17 : 0.0;

    double num = fma(-c, u, v);                // c=0: exactly v
    double den = fma(c, v, u);                 // c=0: exactly u

    double r0 = __builtin_amdgcn_rcp(den);
    r0 = fma(fma(-den, r0, 1.0), r0, r0);      // single NR: r0 err ~max(e^2, 2^-52)
    double q0 = num * r0;
    double xq = fma(fma(-den, q0, num), r0, q0);   // residual-corrected, ~0.5 ulp
    // xq in [-0.1716, 0.4143] — inside fdlibm poly range [0, 0.4375]

    double z = xq * xq;
    double w = z * z;
    double s1_ = z * fma(w, fma(w, fma(w, fma(w, fma(w, aT10, aT8), aT6), aT4), aT2), aT0);
    double s2_ = w * fma(w, fma(w, fma(w, fma(w, aT9, aT7), aT5), aT3), aT1);
    double T   = fma(xq, s1_ + s2_, -atc_lo);      // == (p - atc_lo) to ~0.5ulp
    double res = atc_hi - (T - xq);                // angle of (u,v)

    double res2 = (1.57079632679489655800e+00 - res) + 6.12323399573676603587e-17;
    res = (ayf > axf) ? res2 : res;                // angle of (|x|,|y|)
    double res3 = (3.14159265358979311600e+00 - res) + 1.22464679914735317723e-16;
    res = (fx < 0.0f) ? res3 : res;                // x<0 half-plane
    res = copysign(res, (double)fy);
    return (float)res;
}

// DPP lane-shift helpers (VALU, no LDS): value of lane-1 / lane+1 within
// 16-lane DPP rows. Lanes receiving cross-row garbage are exactly the
// edge-clamped ones (cb==0 / cb==28), overridden by the caller's select.
__device__ __forceinline__ float dpp_prev(float x) {
    int i = __builtin_bit_cast(int, x);
    int r = __builtin_amdgcn_update_dpp(i, i, 0x111, 0xf, 0xf, false); // row_shr:1
    return __builtin_bit_cast(float, r);
}
__device__ __forceinline__ float dpp_next(float x) {
    int i = __builtin_bit_cast(int, x);
    int r = __builtin_amdgcn_update_dpp(i, i, 0x101, 0xf, 0xf, false); // row_shl:1
    return __builtin_bit_cast(float, r);
}

// One block = one patch. Bit-exact replication of the numpy reference:
//  - conv taps pre-scaled (exact pow2 products), summed ascending (kh,kw)
//  - mag = sqrt((gx*gx + gy*gy) + eps), contraction off
//  - atan2: slim f64 (above), rounded to f32
//  - /2pi division: Markstein (rcp + fma correction) — 1-ulp-rare class
//  - histogram: per-bin sequential add chain in pixel order, w0 pass then
//    w1 pass (np.add.at semantics), via order-preserving counting sort.
// R9 vs R8: the per-pixel f32 chain (taps, mag, Markstein, weights) is
// processed two-pixels-per-instruction with v_pk_* (same IEEE rounding per
// half, mul/add kept separate). f64 atan2 core / sqrt / floor stay scalar.
// R8 post-mortem: bank conflicts are data-dependent (atomics/scatter/chains),
// not tile reads — swizzle kept (harmless), no further LDS work attempted.
__global__ __launch_bounds__(256)
void patch_orient_kernel(const float* __restrict__ patches, float* __restrict__ out)
{
    __shared__ __align__(16) float tile[PS * PS];      // 4 KiB, column-swizzled
    __shared__ unsigned bm[PS][NBINS];                 // 4.5 KiB  bm[row][bin]
    __shared__ unsigned short pref[PS][NBINS];         // 2.25 KiB word-prefix popcounts
    __shared__ unsigned short cnt[NBINS];
    __shared__ unsigned short start[NBINS];
    __shared__ __align__(16) float s0[1024];           // w0 sorted by (bin, pixel)
    __shared__ __align__(16) float s1[1024];           // w1, same permutation
    __shared__ float hsm[NBINS];

    const int t = threadIdx.x;
    const int b = blockIdx.x;
    const float* p = patches + (size_t)b * (PS * PS);

    #pragma unroll
    for (int i = t; i < PS * NBINS; i += 256) ((unsigned*)bm)[i] = 0u;

    // thread t owns pixels 4t..4t+3: row = t>>3, cols cb..cb+3
    const int row = t >> 3;
    const int cb  = (t & 7) << 2;
    const int rm  = (row == 0)  ? 0  : row - 1;
    const int rp  = (row == 31) ? 31 : row + 1;

    // coalesced 4 KiB load, swizzled store (conflict-free b128)
    *((float4*)&tile[(row << 5) | (cb ^ ((row & 7) << 2))]) = ((const float4*)p)[t];
    __syncthreads();

    // 3 rows x 6 cols window: one swizzled b128 per row + DPP for edge cols
    float win[3][6];
    {
        const int rows[3] = {rm, row, rp};
        #pragma unroll
        for (int r = 0; r < 3; ++r) {
            const int rr = rows[r];
            float4 v = *((const float4*)&tile[(rr << 5) | (cb ^ ((rr & 7) << 2))]);
            float lf = dpp_prev(v.w);              // lane-1's col cb-1
            float rt = dpp_next(v.x);              // lane+1's col cb+4
            win[r][0] = (cb == 0)  ? v.x : lf;     // edge clamp col 0
            win[r][1] = v.x; win[r][2] = v.y; win[r][3] = v.z; win[r][4] = v.w;
            win[r][5] = (cb == 28) ? v.w : rt;     // edge clamp col 31
        }
    }

    const float TWO_PI = 6.2831853071795864769f;   // f32(2*pi) == 2*f32(pi)
    const float PI_F   = 3.14159265358979323846f;
    const float INV2PI = 0.15915493667125701904f;  // RN_f32(1 / f32(2*pi))

    const f32x2 KN8   = {-0.125f, -0.125f};
    const f32x2 KP8   = { 0.125f,  0.125f};
    const f32x2 KN4   = {-0.25f,  -0.25f};
    const f32x2 KP4   = { 0.25f,   0.25f};
    const f32x2 KEPS  = { 1e-8f,   1e-8f};
    const f32x2 K2PI  = { TWO_PI,  TWO_PI};
    const f32x2 KN2PI = {-TWO_PI, -TWO_PI};
    const f32x2 KPI   = { PI_F,    PI_F};
    const f32x2 K36   = { 36.0f,   36.0f};
    const f32x2 KINV  = { INV2PI,  INV2PI};
    const f32x2 KONE  = { 1.0f,    1.0f};

    const unsigned bitbase = 1u << cb;

    float w0r[4], w1r[4];
    int   binr[4];

    #pragma unroll
    for (int pp = 0; pp < 2; ++pp) {
        const int i0 = pp << 1;
        const f32x2 A  = {win[0][i0],     win[0][i0 + 1]};
        const f32x2 Bv = {win[0][i0 + 1], win[0][i0 + 2]};
        const f32x2 C  = {win[0][i0 + 2], win[0][i0 + 3]};
        const f32x2 D  = {win[1][i0],     win[1][i0 + 1]};
        const f32x2 F  = {win[1][i0 + 2], win[1][i0 + 3]};
        const f32x2 G  = {win[2][i0],     win[2][i0 + 1]};
        const f32x2 H  = {win[2][i0 + 1], win[2][i0 + 2]};
        const f32x2 I  = {win[2][i0 + 2], win[2][i0 + 3]};

        // shared exact products (-A/8 used by both gx,gy; +I/8 likewise)
        const f32x2 mA8 = pk_mul(KN8, A);
        const f32x2 pI8 = pk_mul(KP8, I);

        // pre-scaled taps (exact pow2 products), ascending (kh,kw) order —
        // per-half op sequence identical to the scalar chain.
        f32x2 gx = mA8;
        gx = pk_add(gx, pk_mul(KP8, C));
        gx = pk_add(gx, pk_mul(KN4, D));
        gx = pk_add(gx, pk_mul(KP4, F));
        gx = pk_add(gx, pk_mul(KN8, G));
        gx = pk_add(gx, pI8);

        f32x2 gy = mA8;
        gy = pk_add(gy, pk_mul(KN4, Bv));
        gy = pk_add(gy, pk_mul(KN8, C));
        gy = pk_add(gy, pk_mul(KP8, G));
        gy = pk_add(gy, pk_mul(KP4, H));
        gy = pk_add(gy, pI8);

        f32x2 m1 = pk_mul(gx, gx);
        f32x2 m2 = pk_mul(gy, gy);
        f32x2 s  = pk_add(m1, m2);
        s = pk_add(s, KEPS);
        f32x2 mag;
        mag.x = sqrtf(s.x);                        // IEEE sqrt, scalar
        mag.y = sqrtf(s.y);

        f32x2 gxe = pk_add(gx, KEPS);
        f32x2 at;
        at.x = atan2_np(gy.x, gxe.x);
        at.y = atan2_np(gy.y, gxe.y);

        f32x2 ori = pk_add(at, K2PI);
        f32x2 xn  = pk_mul(K36, pk_add(ori, KPI));
        // Markstein correctly-rounded-division surrogate for xn / TWO_PI
        f32x2 q1m  = pk_mul(xn, KINV);
        f32x2 obig = pk_fma(pk_fma(KN2PI, q1m, xn), KINV, q1m);
        f32x2 bo0;
        bo0.x = floorf(obig.x);
        bo0.y = floorf(obig.y);
        f32x2 wo1 = pk_sub(obig, bo0);             // exact (Sterbenz)
        f32x2 w0p = pk_mul(pk_sub(KONE, wo1), mag);
        f32x2 w1p = pk_mul(wo1, mag);

        #pragma unroll
        for (int h = 0; h < 2; ++h) {
            const int i = i0 + h;
            // bo0 provably in [35, 72]; fold to [0,36)
            int bi0 = (int)(h ? bo0.y : bo0.x) - 36;
            if (bi0 < 0)   bi0 += 36;              // 35 -> 35
            if (bi0 >= 36) bi0 -= 36;              // 72 -> 0
            w0r[i]  = h ? w0p.y : w0p.x;
            w1r[i]  = h ? w1p.y : w1p.x;
            binr[i] = bi0;
            atomicOr(&bm[row][bi0], bitbase << i);
        }
    }
    __syncthreads();

    // wave 0: per-bin word-prefix popcounts + counts + bin-start prefix.
    // Loads batched 8-wide so the compiler pipelines the LDS round-trips.
    if (t < 64) {
        unsigned run = 0;
        if (t < NBINS) {
            #pragma unroll
            for (int w = 0; w < PS; w += 8) {
                unsigned m0 = bm[w + 0][t], m1 = bm[w + 1][t];
                unsigned m2 = bm[w + 2][t], m3 = bm[w + 3][t];
                unsigned m4 = bm[w + 4][t], m5 = bm[w + 5][t];
                unsigned m6 = bm[w + 6][t], m7 = bm[w + 7][t];
                pref[w + 0][t] = (unsigned short)run; run += __popc(m0);
                pref[w + 1][t] = (unsigned short)run; run += __popc(m1);
                pref[w + 2][t] = (unsigned short)run; run += __popc(m2);
                pref[w + 3][t] = (unsigned short)run; run += __popc(m3);
                pref[w + 4][t] = (unsigned short)run; run += __popc(m4);
                pref[w + 5][t] = (unsigned short)run; run += __popc(m5);
                pref[w + 6][t] = (unsigned short)run; run += __popc(m6);
                pref[w + 7][t] = (unsigned short)run; run += __popc(m7);
            }
            cnt[t] = (unsigned short)run;
        }
        // exclusive prefix over bins (wave-wide shfl scan; lanes >=36 hold 0)
        unsigned v = run;
        #pragma unroll
        for (int d = 1; d < 64; d <<= 1) {
            unsigned o = (unsigned)__shfl_up((int)v, d);
            if (t >= d) v += o;
        }
        if (t < NBINS) start[t] = (unsigned short)(v - run);
    }
    __syncthreads();

    // scatter weights from registers into bin-sorted order (stable by pixel)
    #pragma unroll
    for (int i = 0; i < 4; ++i) {
        const int bi = binr[i];
        const unsigned lowmask = (bitbase << i) - 1u;
        const int pos = (int)start[bi] + (int)pref[row][bi]
                      + __popc(bm[row][bi] & lowmask);
        s0[pos] = w0r[i];
        s1[pos] = w1r[i];
    }
    __syncthreads();

    // exact np.add.at chains: bin t = (w0 run of bin t) then (w1 run of bin t-1)
    // unroll 4 (order preserved) to batch the LDS loads.
    if (t < NBINS) {
        float acc = 0.0f;
        {
            int i = start[t], en = i + cnt[t];
            for (; i + 3 < en; i += 4) {
                acc += s0[i]; acc += s0[i + 1]; acc += s0[i + 2]; acc += s0[i + 3];
            }
            for (; i < en; ++i) acc += s0[i];
        }
        {
            int t2 = (t == 0) ? NBINS - 1 : t - 1;
            int i = start[t2], en = i + cnt[t2];
            for (; i + 3 < en; i += 4) {
                acc += s1[i]; acc += s1[i + 1]; acc += s1[i + 2]; acc += s1[i + 3];
            }
            for (; i < en; ++i) acc += s1[i];
        }
        hsm[t] = acc * (1.0f / 1024.0f);           // /npix, exact pow2
    }
    __syncthreads();

    // parallel smoothing + butterfly argmax (min index on ties == np.argmax)
    if (t < 64) {
        float val = -1.0f;                          // all sm >= 0
        int   idx = t;
        if (t < NBINS) {
            int im_ = (t == 0)         ? NBINS - 1 : t - 1;
            int ip_ = (t == NBINS - 1) ? 0         : t + 1;
            float q0 = 0.33f * hsm[im_];
            float q1 = 0.34f * hsm[t];
            float q2 = 0.33f * hsm[ip_];
            float val_ = (q0 + q1) + q2;            // left-to-right, no FMA
            val = val_;
        }
        #pragma unroll
        for (int d = 1; d < 64; d <<= 1) {
            float ov = __shfl_xor(val, d);
            int   oi = __shfl_xor(idx, d);
            if (ov > val || (ov == val && oi < idx)) { val = ov; idx = oi; }
        }
        if (t == 0) {
            float t1 = TWO_PI * (float)idx;
            float t2 = t1 / 36.0f;
            float t3 = t2 - PI_F;
            out[b] = -t3;
        }
    }
}

extern "C" void kernel_launch(void* const* d_in, const int* in_sizes, int n_in,
                              void* d_out, int out_size, void* d_ws, size_t ws_size,
                              hipStream_t stream) {
    const float* patch = (const float*)d_in[0];
    float* out = (float*)d_out;
    const int B = in_sizes[0] / (PS * PS);   // 65536 patches
    patch_orient_kernel<<<B, 256, 0, stream>>>(patch, out);
}

// Round 3
// 491.903 us; speedup vs baseline: 1.0049x; 1.0049x over previous
//
#include <hip/hip_runtime.h>
#include <math.h>

#pragma clang fp contract(off)

#define NBINS 36
#define PS 32

typedef float f32x2 __attribute__((ext_vector_type(2)));

// CDNA packed-f32 VOP3P (full-rate, gfx90a+): IEEE f32 per half, identical
// rounding to scalar v_mul/v_add/v_fma. Emitted via asm so mul/add stay
// separate (contract off) and packing is guaranteed.
__device__ __forceinline__ f32x2 pk_mul(f32x2 a, f32x2 b) {
    f32x2 d;
    asm("v_pk_mul_f32 %0, %1, %2" : "=v"(d) : "v"(a), "v"(b));
    return d;
}
__device__ __forceinline__ f32x2 pk_add(f32x2 a, f32x2 b) {
    f32x2 d;
    asm("v_pk_add_f32 %0, %1, %2" : "=v"(d) : "v"(a), "v"(b));
    return d;
}
__device__ __forceinline__ f32x2 pk_sub(f32x2 a, f32x2 b) {   // a + (-b), IEEE == a-b
    f32x2 d;
    asm("v_pk_add_f32 %0, %1, %2 neg_lo:[0,1] neg_hi:[0,1]" : "=v"(d) : "v"(a), "v"(b));
    return d;
}
__device__ __forceinline__ f32x2 pk_fma(f32x2 a, f32x2 b, f32x2 c) {
    f32x2 d;
    asm("v_pk_fma_f32 %0, %1, %2, %3" : "=v"(d) : "v"(a), "v"(b), "v"(c));
    return d;
}

// Slim branchless f64 atan2, rounded to f32 (absmax 0.0 R5-R9).
__device__ __forceinline__ float atan2_np(float fy, float fx)
{
    const double aT0  =  3.33333333333329318027e-01;
    const double aT1  = -1.99999999998764832476e-01;
    const double aT2  =  1.42857142725034663711e-01;
    const double aT3  = -1.11111104054623557880e-01;
    const double aT4  =  9.09088713343650656196e-02;
    const double aT5  = -7.69187620504482999495e-02;
    const double aT6  =  6.66107313738753120669e-02;
    const double aT7  = -5.83357013379057348645e-02;
    const double aT8  =  4.97687799461593236017e-02;
    const double aT9  = -3.65315727442169155270e-02;
    const double aT10 =  1.62858201153657823623e-02;

    float axf = fabsf(fx), ayf = fabsf(fy);
    float uf = fmaxf(axf, ayf), vf = fminf(axf, ayf);
    bool g1 = vf >= 0.41421356f * uf;          // ~tan(pi/8); either branch valid near cut

    double u = (double)uf, v = (double)vf;
    double c      = g1 ? 1.0 : 0.0;
    double atc_hi = g1 ? 7.85398163397448278999e-01 : 0.0;
    double atc_lo = g1 ? 3.06161699786838301793e-17 : 0.0;

    double num = fma(-c, u, v);                // c=0: exactly v
    double den = fma(c, v, u);                 // c=0: exactly u

    double r0 = __builtin_amdgcn_rcp(den);
    r0 = fma(fma(-den, r0, 1.0), r0, r0);      // single NR: r0 err ~max(e^2, 2^-52)
    double q0 = num * r0;
    double xq = fma(fma(-den, q0, num), r0, q0);   // residual-corrected, ~0.5 ulp
    // xq in [-0.1716, 0.4143] — inside fdlibm poly range [0, 0.4375]

    double z = xq * xq;
    double w = z * z;
    double s1_ = z * fma(w, fma(w, fma(w, fma(w, fma(w, aT10, aT8), aT6), aT4), aT2), aT0);
    double s2_ = w * fma(w, fma(w, fma(w, fma(w, aT9, aT7), aT5), aT3), aT1);
    double T   = fma(xq, s1_ + s2_, -atc_lo);      // == (p - atc_lo) to ~0.5ulp
    double res = atc_hi - (T - xq);                // angle of (u,v)

    double res2 = (1.57079632679489655800e+00 - res) + 6.12323399573676603587e-17;
    res = (ayf > axf) ? res2 : res;                // angle of (|x|,|y|)
    double res3 = (3.14159265358979311600e+00 - res) + 1.22464679914735317723e-16;
    res = (fx < 0.0f) ? res3 : res;                // x<0 half-plane
    res = copysign(res, (double)fy);
    return (float)res;
}

// DPP lane-shift helpers (VALU, no LDS): value of lane-1 / lane+1 within
// 16-lane DPP rows. Lanes receiving cross-row garbage are exactly the
// edge-clamped ones (cb==0 / cb==28), overridden by the caller's select.
__device__ __forceinline__ float dpp_prev(float x) {
    int i = __builtin_bit_cast(int, x);
    int r = __builtin_amdgcn_update_dpp(i, i, 0x111, 0xf, 0xf, false); // row_shr:1
    return __builtin_bit_cast(float, r);
}
__device__ __forceinline__ float dpp_next(float x) {
    int i = __builtin_bit_cast(int, x);
    int r = __builtin_amdgcn_update_dpp(i, i, 0x101, 0xf, 0xf, false); // row_shl:1
    return __builtin_bit_cast(float, r);
}

// One block = one patch. Bit-exact replication of the numpy reference.
// R10 vs R9: the three serial epilogue phases (prefix-popcount, add-chains,
// argmax) ran on wave 0 of EVERY block; with wave i -> SIMD i%4, all resident
// blocks' ~750-cycle epilogues piled onto SIMD 0 while SIMDs 1-3 idled
// through those phases. Rotate the worker wave by blockIdx&3 so consecutive
// blocks use different SIMDs — identical arithmetic, balanced issue load.
// Also: bm cleared as uint4, patch load issued before the clear.
__global__ __launch_bounds__(256)
void patch_orient_kernel(const float* __restrict__ patches, float* __restrict__ out)
{
    __shared__ __align__(16) float tile[PS * PS];      // 4 KiB, column-swizzled
    __shared__ __align__(16) unsigned bm[PS][NBINS];   // 4.5 KiB  bm[row][bin]
    __shared__ unsigned short pref[PS][NBINS];         // 2.25 KiB word-prefix popcounts
    __shared__ unsigned short cnt[NBINS];
    __shared__ unsigned short start[NBINS];
    __shared__ __align__(16) float s0[1024];           // w0 sorted by (bin, pixel)
    __shared__ __align__(16) float s1[1024];           // w1, same permutation
    __shared__ float hsm[NBINS];

    const int t = threadIdx.x;
    const int b = blockIdx.x;
    const int wv     = t >> 6;                         // wave id 0..3
    const int lane   = t & 63;
    const int worker = b & 3;                          // rotating epilogue wave
    const float* p = patches + (size_t)b * (PS * PS);

    // issue the global load first; clear bm while it is in flight
    const float4 pix = ((const float4*)p)[t];

    {   // bm = 0 : 288 uint4 stores
        const uint4 z4 = {0u, 0u, 0u, 0u};
        ((uint4*)bm)[t] = z4;
        if (t < PS * NBINS / 4 - 256) ((uint4*)bm)[t + 256] = z4;
    }

    // thread t owns pixels 4t..4t+3: row = t>>3, cols cb..cb+3
    const int row = t >> 3;
    const int cb  = (t & 7) << 2;
    const int rm  = (row == 0)  ? 0  : row - 1;
    const int rp  = (row == 31) ? 31 : row + 1;

    // coalesced 4 KiB load, swizzled store (conflict-free b128)
    *((float4*)&tile[(row << 5) | (cb ^ ((row & 7) << 2))]) = pix;
    __syncthreads();

    // 3 rows x 6 cols window: one swizzled b128 per row + DPP for edge cols
    float win[3][6];
    {
        const int rows[3] = {rm, row, rp};
        #pragma unroll
        for (int r = 0; r < 3; ++r) {
            const int rr = rows[r];
            float4 v = *((const float4*)&tile[(rr << 5) | (cb ^ ((rr & 7) << 2))]);
            float lf = dpp_prev(v.w);              // lane-1's col cb-1
            float rt = dpp_next(v.x);              // lane+1's col cb+4
            win[r][0] = (cb == 0)  ? v.x : lf;     // edge clamp col 0
            win[r][1] = v.x; win[r][2] = v.y; win[r][3] = v.z; win[r][4] = v.w;
            win[r][5] = (cb == 28) ? v.w : rt;     // edge clamp col 31
        }
    }

    const float TWO_PI = 6.2831853071795864769f;   // f32(2*pi) == 2*f32(pi)
    const float PI_F   = 3.14159265358979323846f;
    const float INV2PI = 0.15915493667125701904f;  // RN_f32(1 / f32(2*pi))

    const f32x2 KN8   = {-0.125f, -0.125f};
    const f32x2 KP8   = { 0.125f,  0.125f};
    const f32x2 KN4   = {-0.25f,  -0.25f};
    const f32x2 KP4   = { 0.25f,   0.25f};
    const f32x2 KEPS  = { 1e-8f,   1e-8f};
    const f32x2 K2PI  = { TWO_PI,  TWO_PI};
    const f32x2 KN2PI = {-TWO_PI, -TWO_PI};
    const f32x2 KPI   = { PI_F,    PI_F};
    const f32x2 K36   = { 36.0f,   36.0f};
    const f32x2 KINV  = { INV2PI,  INV2PI};
    const f32x2 KONE  = { 1.0f,    1.0f};

    const unsigned bitbase = 1u << cb;

    float w0r[4], w1r[4];
    int   binr[4];

    #pragma unroll
    for (int pp = 0; pp < 2; ++pp) {
        const int i0 = pp << 1;
        const f32x2 A  = {win[0][i0],     win[0][i0 + 1]};
        const f32x2 Bv = {win[0][i0 + 1], win[0][i0 + 2]};
        const f32x2 C  = {win[0][i0 + 2], win[0][i0 + 3]};
        const f32x2 D  = {win[1][i0],     win[1][i0 + 1]};
        const f32x2 F  = {win[1][i0 + 2], win[1][i0 + 3]};
        const f32x2 G  = {win[2][i0],     win[2][i0 + 1]};
        const f32x2 H  = {win[2][i0 + 1], win[2][i0 + 2]};
        const f32x2 I  = {win[2][i0 + 2], win[2][i0 + 3]};

        // shared exact products (-A/8 used by both gx,gy; +I/8 likewise)
        const f32x2 mA8 = pk_mul(KN8, A);
        const f32x2 pI8 = pk_mul(KP8, I);

        // pre-scaled taps (exact pow2 products), ascending (kh,kw) order —
        // per-half op sequence identical to the scalar chain.
        f32x2 gx = mA8;
        gx = pk_add(gx, pk_mul(KP8, C));
        gx = pk_add(gx, pk_mul(KN4, D));
        gx = pk_add(gx, pk_mul(KP4, F));
        gx = pk_add(gx, pk_mul(KN8, G));
        gx = pk_add(gx, pI8);

        f32x2 gy = mA8;
        gy = pk_add(gy, pk_mul(KN4, Bv));
        gy = pk_add(gy, pk_mul(KN8, C));
        gy = pk_add(gy, pk_mul(KP8, G));
        gy = pk_add(gy, pk_mul(KP4, H));
        gy = pk_add(gy, pI8);

        f32x2 m1 = pk_mul(gx, gx);
        f32x2 m2 = pk_mul(gy, gy);
        f32x2 s  = pk_add(m1, m2);
        s = pk_add(s, KEPS);
        f32x2 mag;
        mag.x = sqrtf(s.x);                        // IEEE sqrt, scalar
        mag.y = sqrtf(s.y);

        f32x2 gxe = pk_add(gx, KEPS);
        f32x2 at;
        at.x = atan2_np(gy.x, gxe.x);
        at.y = atan2_np(gy.y, gxe.y);

        f32x2 ori = pk_add(at, K2PI);
        f32x2 xn  = pk_mul(K36, pk_add(ori, KPI));
        // Markstein correctly-rounded-division surrogate for xn / TWO_PI
        f32x2 q1m  = pk_mul(xn, KINV);
        f32x2 obig = pk_fma(pk_fma(KN2PI, q1m, xn), KINV, q1m);
        f32x2 bo0;
        bo0.x = floorf(obig.x);
        bo0.y = floorf(obig.y);
        f32x2 wo1 = pk_sub(obig, bo0);             // exact (Sterbenz)
        f32x2 w0p = pk_mul(pk_sub(KONE, wo1), mag);
        f32x2 w1p = pk_mul(wo1, mag);

        #pragma unroll
        for (int h = 0; h < 2; ++h) {
            const int i = i0 + h;
            // bo0 provably in [35, 72]; fold to [0,36)
            int bi0 = (int)(h ? bo0.y : bo0.x) - 36;
            if (bi0 < 0)   bi0 += 36;              // 35 -> 35
            if (bi0 >= 36) bi0 -= 36;              // 72 -> 0
            w0r[i]  = h ? w0p.y : w0p.x;
            w1r[i]  = h ? w1p.y : w1p.x;
            binr[i] = bi0;
            atomicOr(&bm[row][bi0], bitbase << i);
        }
    }
    __syncthreads();

    // worker wave: per-bin word-prefix popcounts + counts + bin-start prefix.
    // Loads batched 8-wide so the compiler pipelines the LDS round-trips.
    if (wv == worker) {
        unsigned run = 0;
        if (lane < NBINS) {
            #pragma unroll
            for (int w = 0; w < PS; w += 8) {
                unsigned m0 = bm[w + 0][lane], m1 = bm[w + 1][lane];
                unsigned m2 = bm[w + 2][lane], m3 = bm[w + 3][lane];
                unsigned m4 = bm[w + 4][lane], m5 = bm[w + 5][lane];
                unsigned m6 = bm[w + 6][lane], m7 = bm[w + 7][lane];
                pref[w + 0][lane] = (unsigned short)run; run += __popc(m0);
                pref[w + 1][lane] = (unsigned short)run; run += __popc(m1);
                pref[w + 2][lane] = (unsigned short)run; run += __popc(m2);
                pref[w + 3][lane] = (unsigned short)run; run += __popc(m3);
                pref[w + 4][lane] = (unsigned short)run; run += __popc(m4);
                pref[w + 5][lane] = (unsigned short)run; run += __popc(m5);
                pref[w + 6][lane] = (unsigned short)run; run += __popc(m6);
                pref[w + 7][lane] = (unsigned short)run; run += __popc(m7);
            }
            cnt[lane] = (unsigned short)run;
        }
        // exclusive prefix over bins (wave-wide shfl scan; lanes >=36 hold 0)
        unsigned v = run;
        #pragma unroll
        for (int d = 1; d < 64; d <<= 1) {
            unsigned o = (unsigned)__shfl_up((int)v, d);
            if (lane >= d) v += o;
        }
        if (lane < NBINS) start[lane] = (unsigned short)(v - run);
    }
    __syncthreads();

    // scatter weights from registers into bin-sorted order (stable by pixel)
    #pragma unroll
    for (int i = 0; i < 4; ++i) {
        const int bi = binr[i];
        const unsigned lowmask = (bitbase << i) - 1u;
        const int pos = (int)start[bi] + (int)pref[row][bi]
                      + __popc(bm[row][bi] & lowmask);
        s0[pos] = w0r[i];
        s1[pos] = w1r[i];
    }
    __syncthreads();

    // exact np.add.at chains: bin = (w0 run of bin) then (w1 run of bin-1)
    // unroll 4 (order preserved) to batch the LDS loads.
    if (wv == worker && lane < NBINS) {
        float acc = 0.0f;
        {
            int i = start[lane], en = i + cnt[lane];
            for (; i + 3 < en; i += 4) {
                acc += s0[i]; acc += s0[i + 1]; acc += s0[i + 2]; acc += s0[i + 3];
            }
            for (; i < en; ++i) acc += s0[i];
        }
        {
            int t2 = (lane == 0) ? NBINS - 1 : lane - 1;
            int i = start[t2], en = i + cnt[t2];
            for (; i + 3 < en; i += 4) {
                acc += s1[i]; acc += s1[i + 1]; acc += s1[i + 2]; acc += s1[i + 3];
            }
            for (; i < en; ++i) acc += s1[i];
        }
        hsm[lane] = acc * (1.0f / 1024.0f);        // /npix, exact pow2
    }
    __syncthreads();

    // parallel smoothing + butterfly argmax (min index on ties == np.argmax)
    if (wv == worker) {
        float val = -1.0f;                          // all sm >= 0
        int   idx = lane;
        if (lane < NBINS) {
            int im_ = (lane == 0)         ? NBINS - 1 : lane - 1;
            int ip_ = (lane == NBINS - 1) ? 0         : lane + 1;
            float q0 = 0.33f * hsm[im_];
            float q1 = 0.34f * hsm[lane];
            float q2 = 0.33f * hsm[ip_];
            float val_ = (q0 + q1) + q2;            // left-to-right, no FMA
            val = val_;
        }
        #pragma unroll
        for (int d = 1; d < 64; d <<= 1) {
            float ov = __shfl_xor(val, d);
            int   oi = __shfl_xor(idx, d);
            if (ov > val || (ov == val && oi < idx)) { val = ov; idx = oi; }
        }
        if (lane == 0) {
            float t1 = TWO_PI * (float)idx;
            float t2 = t1 / 36.0f;
            float t3 = t2 - PI_F;
            out[b] = -t3;
        }
    }
}

extern "C" void kernel_launch(void* const* d_in, const int* in_sizes, int n_in,
                              void* d_out, int out_size, void* d_ws, size_t ws_size,
                              hipStream_t stream) {
    const float* patch = (const float*)d_in[0];
    float* out = (float*)d_out;
    const int B = in_sizes[0] / (PS * PS);   // 65536 patches
    patch_orient_kernel<<<B, 256, 0, stream>>>(patch, out);
}